// Round 1
// baseline (1813.849 us; speedup 1.0000x reference)
//
#include <hip/hip_runtime.h>

// Problem constants (fixed by setup_inputs)
#define HW_N 4096   // 64*64 spatial positions
#define C_IN 512    // channels
#define C_Q  64     // query/key channels
#define NB   4      // batch

// ---------------------------------------------------------------------------
// Generic fp32 tiled GEMM pieces: BM=BN=64, BK=16, block(16,16), 4x4 microtile
// ---------------------------------------------------------------------------

// out[M,N] = W[M,K] * X[K,N] + bias[M]   (N = HW_N, row-major everywhere)
template <int K>
__global__ __launch_bounds__(256) void gemm_wx(const float* __restrict__ W,
                                               const float* __restrict__ X,
                                               const float* __restrict__ bias,
                                               float* __restrict__ out) {
    __shared__ float sA[16][68];
    __shared__ float sB[16][68];
    const int tx = threadIdx.x, ty = threadIdx.y;
    const int t = ty * 16 + tx;
    const int m0 = blockIdx.y * 64;
    const int n0 = blockIdx.x * 64;

    float acc[4][4] = {};

    for (int k0 = 0; k0 < K; k0 += 16) {
        // A tile: W[m0+mm][k0+kk] -> sA[kk][mm]
        {
            const int mm = t >> 2;
            const int kq = (t & 3) << 2;
            float4 w4 = *(const float4*)(W + (size_t)(m0 + mm) * K + k0 + kq);
            sA[kq + 0][mm] = w4.x;
            sA[kq + 1][mm] = w4.y;
            sA[kq + 2][mm] = w4.z;
            sA[kq + 3][mm] = w4.w;
        }
        // B tile: X[k0+kk][n0+nn] -> sB[kk][nn]
        {
            const int kk = t >> 4;
            const int nq = (t & 15) << 2;
            *(float4*)&sB[kk][nq] = *(const float4*)(X + (size_t)(k0 + kk) * HW_N + n0 + nq);
        }
        __syncthreads();
#pragma unroll
        for (int kk = 0; kk < 16; kk++) {
            float4 a4 = *(const float4*)&sA[kk][ty * 4];
            float4 b4 = *(const float4*)&sB[kk][tx * 4];
            float a[4] = {a4.x, a4.y, a4.z, a4.w};
            float b[4] = {b4.x, b4.y, b4.z, b4.w};
#pragma unroll
            for (int i = 0; i < 4; i++)
#pragma unroll
                for (int j = 0; j < 4; j++)
                    acc[i][j] += a[i] * b[j];
        }
        __syncthreads();
    }

#pragma unroll
    for (int i = 0; i < 4; i++) {
        const int m = m0 + ty * 4 + i;
        const float bi = bias[m];
        float4 o;
        o.x = acc[i][0] + bi;
        o.y = acc[i][1] + bi;
        o.z = acc[i][2] + bi;
        o.w = acc[i][3] + bi;
        *(float4*)&out[(size_t)m * HW_N + n0 + tx * 4] = o;
    }
}

// S[ii,j] = sum_c q[c, iBase+ii] * k[c, j]    (K = C_Q = 64)
__global__ __launch_bounds__(256) void gemm_scores(const float* __restrict__ q,
                                                   const float* __restrict__ k,
                                                   int i0,
                                                   float* __restrict__ S) {
    __shared__ float sA[16][68];
    __shared__ float sB[16][68];
    const int tx = threadIdx.x, ty = threadIdx.y;
    const int t = ty * 16 + tx;
    const int m0 = blockIdx.y * 64;   // ii tile
    const int n0 = blockIdx.x * 64;   // j tile
    const int iBase = i0 + m0;

    float acc[4][4] = {};

    for (int k0 = 0; k0 < C_Q; k0 += 16) {
        {
            const int kk = t >> 4;
            const int mq = (t & 15) << 2;
            *(float4*)&sA[kk][mq] = *(const float4*)(q + (size_t)(k0 + kk) * HW_N + iBase + mq);
        }
        {
            const int kk = t >> 4;
            const int nq = (t & 15) << 2;
            *(float4*)&sB[kk][nq] = *(const float4*)(k + (size_t)(k0 + kk) * HW_N + n0 + nq);
        }
        __syncthreads();
#pragma unroll
        for (int kk = 0; kk < 16; kk++) {
            float4 a4 = *(const float4*)&sA[kk][ty * 4];
            float4 b4 = *(const float4*)&sB[kk][tx * 4];
            float a[4] = {a4.x, a4.y, a4.z, a4.w};
            float b[4] = {b4.x, b4.y, b4.z, b4.w};
#pragma unroll
            for (int i = 0; i < 4; i++)
#pragma unroll
                for (int j = 0; j < 4; j++)
                    acc[i][j] += a[i] * b[j];
        }
        __syncthreads();
    }

#pragma unroll
    for (int i = 0; i < 4; i++) {
        float4 o = {acc[i][0], acc[i][1], acc[i][2], acc[i][3]};
        *(float4*)&S[(size_t)(m0 + ty * 4 + i) * HW_N + n0 + tx * 4] = o;
    }
}

// In-place softmax over each row of S (rows of length HW_N), one block per row
__global__ __launch_bounds__(256) void softmax_rows(float* __restrict__ S) {
    __shared__ float red[256];
    const int t = threadIdx.x;
    float* p = S + (size_t)blockIdx.x * HW_N;

    float vals[16];
    float m = -1e30f;
#pragma unroll
    for (int e = 0; e < 16; e++) {
        vals[e] = p[t + e * 256];
        m = fmaxf(m, vals[e]);
    }
    red[t] = m;
    __syncthreads();
    for (int s = 128; s > 0; s >>= 1) {
        if (t < s) red[t] = fmaxf(red[t], red[t + s]);
        __syncthreads();
    }
    m = red[0];
    __syncthreads();

    float sum = 0.f;
#pragma unroll
    for (int e = 0; e < 16; e++) {
        vals[e] = __expf(vals[e] - m);
        sum += vals[e];
    }
    red[t] = sum;
    __syncthreads();
    for (int s = 128; s > 0; s >>= 1) {
        if (t < s) red[t] += red[t + s];
        __syncthreads();
    }
    const float inv = 1.0f / red[0];
#pragma unroll
    for (int e = 0; e < 16; e++) p[t + e * 256] = vals[e] * inv;
}

// out[c, i0+ii] = alpha * sum_j V[c,j] * A[ii,j]   (K = HW_N)
__global__ __launch_bounds__(256) void gemm_feat(const float* __restrict__ V,
                                                 const float* __restrict__ A,
                                                 const float* __restrict__ alpha,
                                                 float* __restrict__ out,
                                                 int i0) {
    __shared__ float sA[16][68];
    __shared__ float sB[16][68];
    const int tx = threadIdx.x, ty = threadIdx.y;
    const int t = ty * 16 + tx;
    const int m0 = blockIdx.y * 64;  // c tile
    const int n0 = blockIdx.x * 64;  // ii tile

    float acc[4][4] = {};

    for (int k0 = 0; k0 < HW_N; k0 += 16) {
        // A tile: V[m0+mm][k0+kk] -> sA[kk][mm]
        {
            const int mm = t >> 2;
            const int kq = (t & 3) << 2;
            float4 v4 = *(const float4*)(V + (size_t)(m0 + mm) * HW_N + k0 + kq);
            sA[kq + 0][mm] = v4.x;
            sA[kq + 1][mm] = v4.y;
            sA[kq + 2][mm] = v4.z;
            sA[kq + 3][mm] = v4.w;
        }
        // B tile: Attn[n0+nn][k0+kk] -> sB[kk][nn]  (transposed load)
        {
            const int nn = t >> 2;
            const int kq = (t & 3) << 2;
            float4 a4 = *(const float4*)(A + (size_t)(n0 + nn) * HW_N + k0 + kq);
            sB[kq + 0][nn] = a4.x;
            sB[kq + 1][nn] = a4.y;
            sB[kq + 2][nn] = a4.z;
            sB[kq + 3][nn] = a4.w;
        }
        __syncthreads();
#pragma unroll
        for (int kk = 0; kk < 16; kk++) {
            float4 a4 = *(const float4*)&sA[kk][ty * 4];
            float4 b4 = *(const float4*)&sB[kk][tx * 4];
            float a[4] = {a4.x, a4.y, a4.z, a4.w};
            float b[4] = {b4.x, b4.y, b4.z, b4.w};
#pragma unroll
            for (int i = 0; i < 4; i++)
#pragma unroll
                for (int j = 0; j < 4; j++)
                    acc[i][j] += a[i] * b[j];
        }
        __syncthreads();
    }

    const float al = alpha[0];
#pragma unroll
    for (int i = 0; i < 4; i++) {
        const int m = m0 + ty * 4 + i;
        float4 o;
        o.x = al * acc[i][0];
        o.y = al * acc[i][1];
        o.z = al * acc[i][2];
        o.w = al * acc[i][3];
        *(float4*)&out[(size_t)m * HW_N + i0 + n0 + tx * 4] = o;
    }
}

// ---------------------------------------------------------------------------

extern "C" void kernel_launch(void* const* d_in, const int* in_sizes, int n_in,
                              void* d_out, int out_size, void* d_ws, size_t ws_size,
                              hipStream_t stream) {
    const float* x     = (const float*)d_in[0];
    const float* Wq    = (const float*)d_in[1];
    const float* bq    = (const float*)d_in[2];
    const float* Wk    = (const float*)d_in[3];
    const float* bk    = (const float*)d_in[4];
    const float* Wv    = (const float*)d_in[5];
    const float* bv    = (const float*)d_in[6];
    const float* alpha = (const float*)d_in[7];
    float* out = (float*)d_out;

    float* ws   = (float*)d_ws;
    float* qb   = ws;                              // C_Q  * HW_N
    float* kb   = qb + (size_t)C_Q * HW_N;         // C_Q  * HW_N
    float* vb   = kb + (size_t)C_Q * HW_N;         // C_IN * HW_N
    float* attn = vb + (size_t)C_IN * HW_N;        // I * HW_N chunk

    const size_t fixed_bytes = ((size_t)2 * C_Q * HW_N + (size_t)C_IN * HW_N) * sizeof(float);
    size_t remain = ws_size > fixed_bytes ? ws_size - fixed_bytes : 0;
    int I = (int)(remain / ((size_t)HW_N * sizeof(float)));
    if (I > HW_N) I = HW_N;
    I &= ~63;
    if (I < 64) I = 64;  // minimum chunk; ws must provide at least ~12 MB

    const dim3 blk(16, 16);

    for (int b = 0; b < NB; b++) {
        const float* xb = x + (size_t)b * C_IN * HW_N;
        float* outb = out + (size_t)b * C_IN * HW_N;

        gemm_wx<C_IN><<<dim3(HW_N / 64, C_Q / 64), blk, 0, stream>>>(Wq, xb, bq, qb);
        gemm_wx<C_IN><<<dim3(HW_N / 64, C_Q / 64), blk, 0, stream>>>(Wk, xb, bk, kb);
        gemm_wx<C_IN><<<dim3(HW_N / 64, C_IN / 64), blk, 0, stream>>>(Wv, xb, bv, vb);

        for (int i0 = 0; i0 < HW_N; i0 += I) {
            int Icur = HW_N - i0 < I ? HW_N - i0 : I;
            gemm_scores<<<dim3(HW_N / 64, Icur / 64), blk, 0, stream>>>(qb, kb, i0, attn);
            softmax_rows<<<dim3(Icur), dim3(256), 0, stream>>>(attn);
            gemm_feat<<<dim3(Icur / 64, C_IN / 64), blk, 0, stream>>>(vb, attn, alpha, outb, i0);
        }
    }
}

// Round 2
// 1036.915 us; speedup vs baseline: 1.7493x; 1.7493x over previous
//
#include <hip/hip_runtime.h>

// Problem constants (fixed by setup_inputs)
#define HW_N 4096   // 64*64 spatial positions
#define C_IN 512    // channels
#define C_Q  64     // query/key channels
#define NB   4      // batch

typedef __attribute__((ext_vector_type(8))) short short8;
typedef __attribute__((ext_vector_type(4))) float float4v;
typedef unsigned short ushort_t;

// ---------------------------------------------------------------------------
// bf16 helpers (manual, RNE)
// ---------------------------------------------------------------------------
__device__ __forceinline__ ushort_t f2bf(float x) {
    unsigned int u = __float_as_uint(x);
    u = (u + 0x7fffu + ((u >> 16) & 1u)) >> 16;
    return (ushort_t)u;
}
__device__ __forceinline__ float bf2f(ushort_t h) {
    return __uint_as_float(((unsigned int)h) << 16);
}

// async global->LDS, 16 bytes per lane; lds dst must be wave-uniform base
__device__ __forceinline__ void gl2lds16(const ushort_t* g, ushort_t* l) {
    __builtin_amdgcn_global_load_lds(
        (const __attribute__((address_space(1))) unsigned int*)g,
        (__attribute__((address_space(3))) unsigned int*)l,
        16, 0, 0);
}

// ---------------------------------------------------------------------------
// fp32 tiled GEMM: out[M,N] = W[M,K] * X[K,N] + bias[M]
// SPLIT: write bf16 hi/lo pair instead of fp32
// ---------------------------------------------------------------------------
template <int K, bool SPLIT>
__global__ __launch_bounds__(256) void gemm_wx(const float* __restrict__ W,
                                               const float* __restrict__ X,
                                               const float* __restrict__ bias,
                                               float* __restrict__ outF,
                                               ushort_t* __restrict__ outH,
                                               ushort_t* __restrict__ outL) {
    __shared__ float sA[16][68];
    __shared__ float sB[16][68];
    const int tx = threadIdx.x, ty = threadIdx.y;
    const int t = ty * 16 + tx;
    const int m0 = blockIdx.y * 64;
    const int n0 = blockIdx.x * 64;

    float acc[4][4] = {};

    for (int k0 = 0; k0 < K; k0 += 16) {
        {
            const int mm = t >> 2;
            const int kq = (t & 3) << 2;
            float4 w4 = *(const float4*)(W + (size_t)(m0 + mm) * K + k0 + kq);
            sA[kq + 0][mm] = w4.x;
            sA[kq + 1][mm] = w4.y;
            sA[kq + 2][mm] = w4.z;
            sA[kq + 3][mm] = w4.w;
        }
        {
            const int kk = t >> 4;
            const int nq = (t & 15) << 2;
            *(float4*)&sB[kk][nq] = *(const float4*)(X + (size_t)(k0 + kk) * HW_N + n0 + nq);
        }
        __syncthreads();
#pragma unroll
        for (int kk = 0; kk < 16; kk++) {
            float4 a4 = *(const float4*)&sA[kk][ty * 4];
            float4 b4 = *(const float4*)&sB[kk][tx * 4];
            float a[4] = {a4.x, a4.y, a4.z, a4.w};
            float b[4] = {b4.x, b4.y, b4.z, b4.w};
#pragma unroll
            for (int i = 0; i < 4; i++)
#pragma unroll
                for (int j = 0; j < 4; j++)
                    acc[i][j] += a[i] * b[j];
        }
        __syncthreads();
    }

#pragma unroll
    for (int i = 0; i < 4; i++) {
        const int m = m0 + ty * 4 + i;
        const float bi = bias[m];
        if (SPLIT) {
#pragma unroll
            for (int j = 0; j < 4; j++) {
                float v = acc[i][j] + bi;
                ushort_t h = f2bf(v);
                ushort_t l = f2bf(v - bf2f(h));
                outH[(size_t)m * HW_N + n0 + tx * 4 + j] = h;
                outL[(size_t)m * HW_N + n0 + tx * 4 + j] = l;
            }
        } else {
            float4 o;
            o.x = acc[i][0] + bi;
            o.y = acc[i][1] + bi;
            o.z = acc[i][2] + bi;
            o.w = acc[i][3] + bi;
            *(float4*)&outF[(size_t)m * HW_N + n0 + tx * 4] = o;
        }
    }
}

// ---------------------------------------------------------------------------
// S[i,j] = sum_c q[c,i] * k[c,j]   (K = C_Q = 64), fp32
// ---------------------------------------------------------------------------
__global__ __launch_bounds__(256) void gemm_scores(const float* __restrict__ q,
                                                   const float* __restrict__ k,
                                                   float* __restrict__ S) {
    __shared__ float sA[16][68];
    __shared__ float sB[16][68];
    const int tx = threadIdx.x, ty = threadIdx.y;
    const int t = ty * 16 + tx;
    const int m0 = blockIdx.y * 64;
    const int n0 = blockIdx.x * 64;

    float acc[4][4] = {};

    for (int k0 = 0; k0 < C_Q; k0 += 16) {
        {
            const int kk = t >> 4;
            const int mq = (t & 15) << 2;
            *(float4*)&sA[kk][mq] = *(const float4*)(q + (size_t)(k0 + kk) * HW_N + m0 + mq);
        }
        {
            const int kk = t >> 4;
            const int nq = (t & 15) << 2;
            *(float4*)&sB[kk][nq] = *(const float4*)(k + (size_t)(k0 + kk) * HW_N + n0 + nq);
        }
        __syncthreads();
#pragma unroll
        for (int kk = 0; kk < 16; kk++) {
            float4 a4 = *(const float4*)&sA[kk][ty * 4];
            float4 b4 = *(const float4*)&sB[kk][tx * 4];
            float a[4] = {a4.x, a4.y, a4.z, a4.w};
            float b[4] = {b4.x, b4.y, b4.z, b4.w};
#pragma unroll
            for (int i = 0; i < 4; i++)
#pragma unroll
                for (int j = 0; j < 4; j++)
                    acc[i][j] += a[i] * b[j];
        }
        __syncthreads();
    }

#pragma unroll
    for (int i = 0; i < 4; i++) {
        float4 o = {acc[i][0], acc[i][1], acc[i][2], acc[i][3]};
        *(float4*)&S[(size_t)(m0 + ty * 4 + i) * HW_N + n0 + tx * 4] = o;
    }
}

// ---------------------------------------------------------------------------
// Row softmax, in-place over fp32 scores rows; OUTPUT: bf16 hi (first 8KB of
// row) + bf16 lo (second 8KB). Row i: hi at ushort ofs i*8192, lo at +4096.
// ---------------------------------------------------------------------------
__global__ __launch_bounds__(256) void softmax_rows_bf(float* __restrict__ S) {
    __shared__ float red[256];
    const int t = threadIdx.x;
    float* p = S + (size_t)blockIdx.x * HW_N;

    float vals[16];
    float m = -1e30f;
#pragma unroll
    for (int e = 0; e < 16; e++) {
        vals[e] = p[t + e * 256];
        m = fmaxf(m, vals[e]);
    }
    red[t] = m;
    __syncthreads();
    for (int s = 128; s > 0; s >>= 1) {
        if (t < s) red[t] = fmaxf(red[t], red[t + s]);
        __syncthreads();
    }
    m = red[0];
    __syncthreads();

    float sum = 0.f;
#pragma unroll
    for (int e = 0; e < 16; e++) {
        vals[e] = __expf(vals[e] - m);
        sum += vals[e];
    }
    red[t] = sum;
    __syncthreads();
    for (int s = 128; s > 0; s >>= 1) {
        if (t < s) red[t] += red[t + s];
        __syncthreads();
    }
    const float inv = 1.0f / red[0];

    ushort_t* ph = (ushort_t*)p;
#pragma unroll
    for (int e = 0; e < 16; e++) {
        float v = vals[e] * inv;
        ushort_t h = f2bf(v);
        ushort_t l = f2bf(v - bf2f(h));
        ph[t + e * 256] = h;
        ph[HW_N + t + e * 256] = l;
    }
}

// ---------------------------------------------------------------------------
// feat MFMA GEMM (bf16 hi/lo 3-pass): out[m,n] = sum_k V[m,k]*Attn[n,k]
// M=512, N=4096. 128x128 block tile, 4 waves of 64x64, 16x16x32 bf16 MFMA.
// Attn rows: hi at ushort ofs n*8192, lo at n*8192+4096 (k contiguous).
// ---------------------------------------------------------------------------
template <bool FINAL>
__global__ __launch_bounds__(256) void feat_mfma(const ushort_t* __restrict__ Vh,
                                                 const ushort_t* __restrict__ Vl,
                                                 const ushort_t* __restrict__ attn,
                                                 const float* __restrict__ alpha,
                                                 float* __restrict__ outp,
                                                 int kLen, size_t partStride) {
    __shared__ ushort_t sAh[128 * 32];
    __shared__ ushort_t sAl[128 * 32];
    __shared__ ushort_t sBh[128 * 32];
    __shared__ ushort_t sBl[128 * 32];

    const int tid = threadIdx.x;
    const int w = tid >> 6;
    const int lane = tid & 63;
    const int quad = lane >> 4;
    const int lr = lane & 15;
    const int m0 = blockIdx.y * 128;
    const int n0 = blockIdx.x * 128;
    const int k0 = blockIdx.z * kLen;

    // staging: wave w fills one 128x32 bf16 tile per K-iter
    ushort_t* sDst = (w == 0) ? sAh : (w == 1) ? sAl : (w == 2) ? sBh : sBl;
    const ushort_t* gRow0;
    size_t gStep;
    if (w == 0)      { gRow0 = Vh + (size_t)m0 * HW_N;           gStep = HW_N; }
    else if (w == 1) { gRow0 = Vl + (size_t)m0 * HW_N;           gStep = HW_N; }
    else if (w == 2) { gRow0 = attn + (size_t)n0 * 2 * HW_N;        gStep = 2 * HW_N; }
    else             { gRow0 = attn + (size_t)n0 * 2 * HW_N + HW_N; gStep = 2 * HW_N; }
    const int cr = lane >> 2;        // row within 16-row chunk
    const int kp = (lane & 3) * 8;   // k offset within 32
    const ushort_t* gk = gRow0 + (size_t)cr * gStep + kp + k0;

    const int wm = (w & 1) * 64;
    const int wn = (w >> 1) * 64;

    float4v acc[4][4] = {};

    for (int kk = 0; kk < kLen; kk += 32) {
#pragma unroll
        for (int c = 0; c < 8; c++) {
            gl2lds16(gk + (size_t)(c * 16) * gStep + kk, sDst + c * 512);
        }
        __syncthreads();

        short8 a_h[4], a_l[4], b_h[4], b_l[4];
#pragma unroll
        for (int i = 0; i < 4; i++) {
            a_h[i] = *(const short8*)&sAh[(wm + i * 16 + lr) * 32 + quad * 8];
            a_l[i] = *(const short8*)&sAl[(wm + i * 16 + lr) * 32 + quad * 8];
            b_h[i] = *(const short8*)&sBh[(wn + i * 16 + lr) * 32 + quad * 8];
            b_l[i] = *(const short8*)&sBl[(wn + i * 16 + lr) * 32 + quad * 8];
        }
#pragma unroll
        for (int i = 0; i < 4; i++)
#pragma unroll
            for (int j = 0; j < 4; j++) {
                acc[i][j] = __builtin_amdgcn_mfma_f32_16x16x32_bf16(a_h[i], b_h[j], acc[i][j], 0, 0, 0);
                acc[i][j] = __builtin_amdgcn_mfma_f32_16x16x32_bf16(a_h[i], b_l[j], acc[i][j], 0, 0, 0);
                acc[i][j] = __builtin_amdgcn_mfma_f32_16x16x32_bf16(a_l[i], b_h[j], acc[i][j], 0, 0, 0);
            }
        __syncthreads();
    }

    float* o = FINAL ? outp : (outp + (size_t)blockIdx.z * partStride);
    const float scal = FINAL ? alpha[0] : 1.0f;
#pragma unroll
    for (int i = 0; i < 4; i++)
#pragma unroll
        for (int j = 0; j < 4; j++)
#pragma unroll
            for (int r = 0; r < 4; r++) {
                const int m = m0 + wm + i * 16 + quad * 4 + r;
                const int n = n0 + wn + j * 16 + lr;
                o[(size_t)m * HW_N + n] = scal * acc[i][j][r];
            }
}

// out = alpha * (p0 + p1), vectorized float4 over 512*4096 elems
__global__ __launch_bounds__(256) void reduce_alpha(const float4* __restrict__ p0,
                                                    const float4* __restrict__ p1,
                                                    const float* __restrict__ alpha,
                                                    float4* __restrict__ out) {
    const int i = blockIdx.x * 256 + threadIdx.x;
    const float a = alpha[0];
    float4 x = p0[i];
    float4 y = p1[i];
    float4 o;
    o.x = a * (x.x + y.x);
    o.y = a * (x.y + y.y);
    o.z = a * (x.z + y.z);
    o.w = a * (x.w + y.w);
    out[i] = o;
}

// ---------------------------------------------------------------------------

extern "C" void kernel_launch(void* const* d_in, const int* in_sizes, int n_in,
                              void* d_out, int out_size, void* d_ws, size_t ws_size,
                              hipStream_t stream) {
    const float* x     = (const float*)d_in[0];
    const float* Wq    = (const float*)d_in[1];
    const float* bq    = (const float*)d_in[2];
    const float* Wk    = (const float*)d_in[3];
    const float* bk    = (const float*)d_in[4];
    const float* Wv    = (const float*)d_in[5];
    const float* bv    = (const float*)d_in[6];
    const float* alpha = (const float*)d_in[7];
    float* out = (float*)d_out;

    // ws layout (bytes):
    //   qb     : 64*4096 f32   (1 MB)
    //   kb     : 64*4096 f32   (1 MB)
    //   Vh     : 512*4096 bf16 (4 MB)
    //   Vl     : 512*4096 bf16 (4 MB)
    //   scores : 4096*4096 f32 (64 MB) -> becomes attn hi/lo in place
    //   part   : 2 * 512*4096 f32 (16 MB, optional split-K)
    float* qb = (float*)d_ws;
    float* kb = qb + (size_t)C_Q * HW_N;
    ushort_t* Vh = (ushort_t*)(kb + (size_t)C_Q * HW_N);
    ushort_t* Vl = Vh + (size_t)C_IN * HW_N;
    float* scores = (float*)(Vl + (size_t)C_IN * HW_N);
    float* part = scores + (size_t)HW_N * HW_N;

    const size_t base_bytes = ((size_t)2 * C_Q * HW_N * 4) + ((size_t)2 * C_IN * HW_N * 2) +
                              ((size_t)HW_N * HW_N * 4);
    const size_t splitk_bytes = base_bytes + (size_t)2 * C_IN * HW_N * 4;
    const bool use_splitk = (ws_size >= splitk_bytes);

    const dim3 blk16(16, 16);

    for (int b = 0; b < NB; b++) {
        const float* xb = x + (size_t)b * C_IN * HW_N;
        float* outb = out + (size_t)b * C_IN * HW_N;

        gemm_wx<C_IN, false><<<dim3(HW_N / 64, C_Q / 64), blk16, 0, stream>>>(
            Wq, xb, bq, qb, nullptr, nullptr);
        gemm_wx<C_IN, false><<<dim3(HW_N / 64, C_Q / 64), blk16, 0, stream>>>(
            Wk, xb, bk, kb, nullptr, nullptr);
        gemm_wx<C_IN, true><<<dim3(HW_N / 64, C_IN / 64), blk16, 0, stream>>>(
            Wv, xb, bv, nullptr, Vh, Vl);

        gemm_scores<<<dim3(HW_N / 64, HW_N / 64), blk16, 0, stream>>>(qb, kb, scores);
        softmax_rows_bf<<<dim3(HW_N), dim3(256), 0, stream>>>(scores);

        const ushort_t* attn = (const ushort_t*)scores;
        if (use_splitk) {
            feat_mfma<false><<<dim3(HW_N / 128, C_IN / 128, 2), dim3(256), 0, stream>>>(
                Vh, Vl, attn, alpha, part, HW_N / 2, (size_t)C_IN * HW_N);
            reduce_alpha<<<dim3((C_IN * HW_N / 4) / 256), dim3(256), 0, stream>>>(
                (const float4*)part, (const float4*)(part + (size_t)C_IN * HW_N), alpha,
                (float4*)outb);
        } else {
            feat_mfma<true><<<dim3(HW_N / 128, C_IN / 128, 1), dim3(256), 0, stream>>>(
                Vh, Vl, attn, alpha, outb, HW_N, 0);
        }
    }
}

// Round 3
// 761.157 us; speedup vs baseline: 2.3830x; 1.3623x over previous
//
#include <hip/hip_runtime.h>

// Problem constants (fixed by setup_inputs)
#define HW_N 4096   // 64*64 spatial positions
#define C_IN 512    // channels
#define C_Q  64     // query/key channels
#define NB   4      // batch
#define M_Y  640    // Cq + Cq + C stacked output rows

typedef __attribute__((ext_vector_type(8))) short short8;
typedef __attribute__((ext_vector_type(4))) float float4v;
typedef unsigned short ushort_t;

__device__ __forceinline__ ushort_t f2bf(float x) {
    unsigned int u = __float_as_uint(x);
    u = (u + 0x7fffu + ((u >> 16) & 1u)) >> 16;
    return (ushort_t)u;
}
__device__ __forceinline__ float bf2f(ushort_t h) {
    return __uint_as_float(((unsigned int)h) << 16);
}
__device__ __forceinline__ void gl2lds16(const ushort_t* g, ushort_t* l) {
    __builtin_amdgcn_global_load_lds(
        (const __attribute__((address_space(1))) unsigned int*)g,
        (__attribute__((address_space(3))) unsigned int*)l, 16, 0, 0);
}

// ---------------------------------------------------------------------------
// split stacked W = [Wq;Wk;Wv] (640x512 fp32) -> bf16 hi/lo
// ---------------------------------------------------------------------------
__global__ __launch_bounds__(256) void split_w(const float* __restrict__ Wq,
                                               const float* __restrict__ Wk,
                                               const float* __restrict__ Wv,
                                               ushort_t* __restrict__ Wh,
                                               ushort_t* __restrict__ Wl) {
    int idx = (blockIdx.x * 256 + threadIdx.x) * 4;
#pragma unroll
    for (int e = 0; e < 4; e++) {
        int i = idx + e;
        int m = i >> 9, k = i & 511;
        float v = (m < C_Q) ? Wq[m * C_IN + k]
                 : (m < 2 * C_Q) ? Wk[(m - C_Q) * C_IN + k]
                 : Wv[(size_t)(m - 2 * C_Q) * C_IN + k];
        ushort_t h = f2bf(v);
        Wh[i] = h;
        Wl[i] = f2bf(v - bf2f(h));
    }
}

// ---------------------------------------------------------------------------
// transpose + split: x [512][4096] fp32 -> xT hi/lo [4096][512] bf16
// ---------------------------------------------------------------------------
__global__ __launch_bounds__(256) void split_x(const float* __restrict__ x,
                                               ushort_t* __restrict__ xTh,
                                               ushort_t* __restrict__ xTl) {
    __shared__ float tile[64][65];
    const int n0 = blockIdx.x * 64, k0 = blockIdx.y * 64;
    const int t = threadIdx.x;
#pragma unroll
    for (int it = 0; it < 4; it++) {
        int e = t + it * 256;
        int r = e >> 4, c4 = (e & 15) << 2;
        float4 v = *(const float4*)(x + (size_t)(k0 + r) * HW_N + n0 + c4);
        tile[r][c4 + 0] = v.x; tile[r][c4 + 1] = v.y;
        tile[r][c4 + 2] = v.z; tile[r][c4 + 3] = v.w;
    }
    __syncthreads();
    const int rr = t >> 2, kq = (t & 3) << 4;
    ushort_t h[16], l[16];
#pragma unroll
    for (int j = 0; j < 16; j++) {
        float v = tile[kq + j][rr];
        h[j] = f2bf(v);
        l[j] = f2bf(v - bf2f(h[j]));
    }
    size_t o = (size_t)(n0 + rr) * C_IN + k0 + kq;
    *(uint4*)(xTh + o) = *(uint4*)h;
    *(uint4*)(xTh + o + 8) = *(uint4*)(h + 8);
    *(uint4*)(xTl + o) = *(uint4*)l;
    *(uint4*)(xTl + o + 8) = *(uint4*)(l + 8);
}

// ---------------------------------------------------------------------------
// Generic 3-MFMA bf16 hi/lo GEMM: C[m,n] = sum_k A[m,k]*B[n,k]
// 128 x TN block tile, 4 waves, 16x16x32 bf16 MFMA.
// EPI 0: Y epilogue (+bias, split bf16 h/l; m<128 -> qkT transposed scatter,
//        m>=128 -> V natural). EPI 1: fp32 store. EPI 2: fp32 partial store.
// ---------------------------------------------------------------------------
template <int EPI, int TN>
__global__ __launch_bounds__(256) void mfma3(
    const ushort_t* __restrict__ Ah, const ushort_t* __restrict__ Al, int aStride,
    const ushort_t* __restrict__ Bh, const ushort_t* __restrict__ Bl, int bStride,
    int kLen,
    const float* __restrict__ bq, const float* __restrict__ bk,
    const float* __restrict__ bv,
    ushort_t* __restrict__ qkTh, ushort_t* __restrict__ qkTl,
    ushort_t* __restrict__ Vh, ushort_t* __restrict__ Vl,
    float* __restrict__ outF, size_t partStride) {
    __shared__ ushort_t sAh[128 * 32];
    __shared__ ushort_t sAl[128 * 32];
    __shared__ ushort_t sBh[TN * 32];
    __shared__ ushort_t sBl[TN * 32];

    const int tid = threadIdx.x, w = tid >> 6, lane = tid & 63;
    const int quad = lane >> 4, lr = lane & 15;
    const int m0 = blockIdx.y * 128, n0 = blockIdx.x * TN;
    const int k0 = blockIdx.z * kLen;

    const ushort_t* src;
    ushort_t* dst;
    int stride, rowBase, nchunk;
    if (w == 0)      { src = Ah; dst = sAh; stride = aStride; rowBase = m0; nchunk = 8; }
    else if (w == 1) { src = Al; dst = sAl; stride = aStride; rowBase = m0; nchunk = 8; }
    else if (w == 2) { src = Bh; dst = sBh; stride = bStride; rowBase = n0; nchunk = TN / 16; }
    else             { src = Bl; dst = sBl; stride = bStride; rowBase = n0; nchunk = TN / 16; }
    const int cr = lane >> 2, kp = (lane & 3) << 3;
    const ushort_t* gk = src + (size_t)(rowBase + cr) * stride + kp + k0;

    constexpr int NF = TN / 32;
    const int wm = (w & 1) * 64, wn = (w >> 1) * (TN / 2);

    float4v acc[4][NF];
#pragma unroll
    for (int i = 0; i < 4; i++)
#pragma unroll
        for (int j = 0; j < NF; j++) acc[i][j] = (float4v){0.f, 0.f, 0.f, 0.f};

    for (int kk = 0; kk < kLen; kk += 32) {
        for (int c = 0; c < nchunk; c++)
            gl2lds16(gk + (size_t)(c * 16) * stride + kk, dst + c * 512);
        __syncthreads();

        short8 ah[4], al[4], bh[NF], bl[NF];
#pragma unroll
        for (int i = 0; i < 4; i++) {
            ah[i] = *(const short8*)&sAh[(wm + i * 16 + lr) * 32 + quad * 8];
            al[i] = *(const short8*)&sAl[(wm + i * 16 + lr) * 32 + quad * 8];
        }
#pragma unroll
        for (int j = 0; j < NF; j++) {
            bh[j] = *(const short8*)&sBh[(wn + j * 16 + lr) * 32 + quad * 8];
            bl[j] = *(const short8*)&sBl[(wn + j * 16 + lr) * 32 + quad * 8];
        }
#pragma unroll
        for (int i = 0; i < 4; i++)
#pragma unroll
            for (int j = 0; j < NF; j++) {
                acc[i][j] = __builtin_amdgcn_mfma_f32_16x16x32_bf16(ah[i], bh[j], acc[i][j], 0, 0, 0);
                acc[i][j] = __builtin_amdgcn_mfma_f32_16x16x32_bf16(ah[i], bl[j], acc[i][j], 0, 0, 0);
                acc[i][j] = __builtin_amdgcn_mfma_f32_16x16x32_bf16(al[i], bh[j], acc[i][j], 0, 0, 0);
            }
        __syncthreads();
    }

    if (EPI == 0) {
#pragma unroll
        for (int i = 0; i < 4; i++)
#pragma unroll
            for (int j = 0; j < NF; j++)
#pragma unroll
                for (int r = 0; r < 4; r++) {
                    const int m = m0 + wm + i * 16 + quad * 4 + r;
                    const int n = n0 + wn + j * 16 + lr;
                    float bi = (m < C_Q) ? bq[m]
                              : (m < 2 * C_Q) ? bk[m - C_Q] : bv[m - 2 * C_Q];
                    float v = acc[i][j][r] + bi;
                    ushort_t h = f2bf(v);
                    ushort_t lo = f2bf(v - bf2f(h));
                    if (m < 2 * C_Q) {
                        qkTh[(size_t)n * (2 * C_Q) + m] = h;
                        qkTl[(size_t)n * (2 * C_Q) + m] = lo;
                    } else {
                        Vh[(size_t)(m - 2 * C_Q) * HW_N + n] = h;
                        Vl[(size_t)(m - 2 * C_Q) * HW_N + n] = lo;
                    }
                }
    } else {
        float* o = (EPI == 2) ? (outF + (size_t)blockIdx.z * partStride) : outF;
#pragma unroll
        for (int i = 0; i < 4; i++)
#pragma unroll
            for (int j = 0; j < NF; j++)
#pragma unroll
                for (int r = 0; r < 4; r++) {
                    const int m = m0 + wm + i * 16 + quad * 4 + r;
                    const int n = n0 + wn + j * 16 + lr;
                    o[(size_t)m * HW_N + n] = acc[i][j][r];
                }
    }
}

// ---------------------------------------------------------------------------
// Row softmax in place over fp32 scores; writes bf16 hi (ofs 0) + lo (ofs 4096)
// within each 8192-ushort row.
// ---------------------------------------------------------------------------
__global__ __launch_bounds__(256) void softmax_rows_bf(float* __restrict__ S) {
    __shared__ float red[256];
    const int t = threadIdx.x;
    float* p = S + (size_t)blockIdx.x * HW_N;

    float vals[16];
    float m = -1e30f;
#pragma unroll
    for (int e = 0; e < 16; e++) {
        vals[e] = p[t + e * 256];
        m = fmaxf(m, vals[e]);
    }
    red[t] = m;
    __syncthreads();
    for (int s = 128; s > 0; s >>= 1) {
        if (t < s) red[t] = fmaxf(red[t], red[t + s]);
        __syncthreads();
    }
    m = red[0];
    __syncthreads();

    float sum = 0.f;
#pragma unroll
    for (int e = 0; e < 16; e++) {
        vals[e] = __expf(vals[e] - m);
        sum += vals[e];
    }
    red[t] = sum;
    __syncthreads();
    for (int s = 128; s > 0; s >>= 1) {
        if (t < s) red[t] += red[t + s];
        __syncthreads();
    }
    const float inv = 1.0f / red[0];

    ushort_t* ph = (ushort_t*)p;
#pragma unroll
    for (int e = 0; e < 16; e++) {
        float v = vals[e] * inv;
        ushort_t h = f2bf(v);
        ushort_t l = f2bf(v - bf2f(h));
        ph[t + e * 256] = h;
        ph[HW_N + t + e * 256] = l;
    }
}

// out = alpha * sum_z part[z], float4-vectorized
__global__ __launch_bounds__(256) void reduce_alpha(const float4* __restrict__ part,
                                                    int kparts, size_t stride4,
                                                    const float* __restrict__ alpha,
                                                    float4* __restrict__ out) {
    const size_t i = (size_t)blockIdx.x * 256 + threadIdx.x;
    const float a = alpha[0];
    float4 s = part[i];
    for (int z = 1; z < kparts; z++) {
        float4 p = part[i + (size_t)z * stride4];
        s.x += p.x; s.y += p.y; s.z += p.z; s.w += p.w;
    }
    float4 o;
    o.x = a * s.x; o.y = a * s.y; o.z = a * s.z; o.w = a * s.w;
    out[i] = o;
}

// ---------------------------------------------------------------------------

extern "C" void kernel_launch(void* const* d_in, const int* in_sizes, int n_in,
                              void* d_out, int out_size, void* d_ws, size_t ws_size,
                              hipStream_t stream) {
    const float* x     = (const float*)d_in[0];
    const float* Wq    = (const float*)d_in[1];
    const float* bq    = (const float*)d_in[2];
    const float* Wk    = (const float*)d_in[3];
    const float* bk    = (const float*)d_in[4];
    const float* Wv    = (const float*)d_in[5];
    const float* bv    = (const float*)d_in[6];
    const float* alpha = (const float*)d_in[7];
    float* out = (float*)d_out;

    // ws layout:
    //   qkTh/qkTl : 4096 x 128 bf16 each            (2.1 MB)
    //   Vh/Vl     : 512 x 4096 bf16 each            (8.4 MB)
    //   scores    : 4096 x 4096 fp32                (67.1 MB) -> attn h/l in place
    //     overlay (dead before scores written): xTh/xTl (8.4 MB), Wh/Wl (1.3 MB)
    //   part      : kparts x 512 x 4096 fp32
    ushort_t* qkTh = (ushort_t*)d_ws;
    ushort_t* qkTl = qkTh + (size_t)HW_N * 2 * C_Q;
    ushort_t* Vh   = qkTl + (size_t)HW_N * 2 * C_Q;
    ushort_t* Vl   = Vh + (size_t)C_IN * HW_N;
    float* scores  = (float*)(Vl + (size_t)C_IN * HW_N);
    float* part    = scores + (size_t)HW_N * HW_N;

    ushort_t* xTh = (ushort_t*)scores;
    ushort_t* xTl = xTh + (size_t)HW_N * C_IN;
    ushort_t* Wh  = xTl + (size_t)HW_N * C_IN;
    ushort_t* Wl  = Wh + (size_t)M_Y * C_IN;

    const size_t fixed_bytes = (size_t)HW_N * 2 * C_Q * 2 * 2    // qkT h+l
                             + (size_t)C_IN * HW_N * 2 * 2       // V h+l
                             + (size_t)HW_N * HW_N * 4;          // scores
    const size_t part_bytes = (size_t)C_IN * HW_N * 4;
    const int kparts = (ws_size >= fixed_bytes + 4 * part_bytes) ? 4 : 2;

    for (int b = 0; b < NB; b++) {
        const float* xb = x + (size_t)b * C_IN * HW_N;
        float* outb = out + (size_t)b * C_IN * HW_N;

        split_w<<<dim3(M_Y * C_IN / 4 / 256), dim3(256), 0, stream>>>(Wq, Wk, Wv, Wh, Wl);
        split_x<<<dim3(HW_N / 64, C_IN / 64), dim3(256), 0, stream>>>(xb, xTh, xTl);

        // Y = W*x + b -> qkT (transposed, m<128) and V (m>=128), bf16 h/l
        mfma3<0, 128><<<dim3(HW_N / 128, M_Y / 128), dim3(256), 0, stream>>>(
            Wh, Wl, C_IN, xTh, xTl, C_IN, C_IN,
            bq, bk, bv, qkTh, qkTl, Vh, Vl, nullptr, 0);

        // S[i,j] = sum_c q[c,i]k[c,j]
        mfma3<1, 128><<<dim3(HW_N / 128, HW_N / 128), dim3(256), 0, stream>>>(
            qkTh, qkTl, 2 * C_Q, qkTh + C_Q, qkTl + C_Q, 2 * C_Q, C_Q,
            nullptr, nullptr, nullptr, nullptr, nullptr, nullptr, nullptr,
            scores, 0);

        softmax_rows_bf<<<dim3(HW_N), dim3(256), 0, stream>>>(scores);

        // feat partials: out[c,i] = sum_j V[c,j]*attn[i,j]
        const ushort_t* attn = (const ushort_t*)scores;
        mfma3<2, 64><<<dim3(HW_N / 64, C_IN / 128, kparts), dim3(256), 0, stream>>>(
            Vh, Vl, HW_N, attn, attn + HW_N, 2 * HW_N, HW_N / kparts,
            nullptr, nullptr, nullptr, nullptr, nullptr, nullptr, nullptr,
            part, (size_t)C_IN * HW_N);

        reduce_alpha<<<dim3((C_IN * HW_N / 4) / 256), dim3(256), 0, stream>>>(
            (const float4*)part, kparts, (size_t)C_IN * HW_N / 4, alpha,
            (float4*)outb);
    }
}

// Round 4
// 681.416 us; speedup vs baseline: 2.6619x; 1.1170x over previous
//
#include <hip/hip_runtime.h>
#include <hip/hip_fp16.h>

// Problem constants (fixed by setup_inputs)
#define HW_N 4096   // 64*64 spatial positions
#define C_IN 512    // channels
#define C_Q  64     // query/key channels
#define NB   4      // batch
#define M_Y  640    // Cq + Cq + C stacked output rows

typedef __attribute__((ext_vector_type(8))) short short8;
typedef __attribute__((ext_vector_type(4))) float float4v;
typedef unsigned short ushort_t;

__device__ __forceinline__ ushort_t f2h(float x) {
    return __half_as_ushort(__float2half(x));  // RNE
}
__device__ __forceinline__ float h2f(ushort_t h) {
    return __half2float(__ushort_as_half(h));
}
__device__ __forceinline__ void gl2lds16(const ushort_t* g, ushort_t* l) {
    __builtin_amdgcn_global_load_lds(
        (const __attribute__((address_space(1))) unsigned int*)g,
        (__attribute__((address_space(3))) unsigned int*)l, 16, 0, 0);
}

// ---------------------------------------------------------------------------
// split stacked W = [Wq;Wk;Wv] (640x512 fp32) -> fp16 hi/lo
// ---------------------------------------------------------------------------
__global__ __launch_bounds__(256) void split_w(const float* __restrict__ Wq,
                                               const float* __restrict__ Wk,
                                               const float* __restrict__ Wv,
                                               ushort_t* __restrict__ Wh,
                                               ushort_t* __restrict__ Wl) {
    int idx = (blockIdx.x * 256 + threadIdx.x) * 4;
#pragma unroll
    for (int e = 0; e < 4; e++) {
        int i = idx + e;
        int m = i >> 9, k = i & 511;
        float v = (m < C_Q) ? Wq[m * C_IN + k]
                 : (m < 2 * C_Q) ? Wk[(m - C_Q) * C_IN + k]
                 : Wv[(size_t)(m - 2 * C_Q) * C_IN + k];
        ushort_t h = f2h(v);
        Wh[i] = h;
        Wl[i] = f2h(v - h2f(h));
    }
}

// ---------------------------------------------------------------------------
// transpose + split: x [512][4096] fp32 -> xT hi/lo [4096][512] fp16
// ---------------------------------------------------------------------------
__global__ __launch_bounds__(256) void split_x(const float* __restrict__ x,
                                               ushort_t* __restrict__ xTh,
                                               ushort_t* __restrict__ xTl) {
    __shared__ float tile[64][65];
    const int n0 = blockIdx.x * 64, k0 = blockIdx.y * 64;
    const int t = threadIdx.x;
#pragma unroll
    for (int it = 0; it < 4; it++) {
        int e = t + it * 256;
        int r = e >> 4, c4 = (e & 15) << 2;
        float4 v = *(const float4*)(x + (size_t)(k0 + r) * HW_N + n0 + c4);
        tile[r][c4 + 0] = v.x; tile[r][c4 + 1] = v.y;
        tile[r][c4 + 2] = v.z; tile[r][c4 + 3] = v.w;
    }
    __syncthreads();
    const int rr = t >> 2, kq = (t & 3) << 4;
    ushort_t h[16], l[16];
#pragma unroll
    for (int j = 0; j < 16; j++) {
        float v = tile[kq + j][rr];
        h[j] = f2h(v);
        l[j] = f2h(v - h2f(h[j]));
    }
    size_t o = (size_t)(n0 + rr) * C_IN + k0 + kq;
    *(uint4*)(xTh + o) = *(uint4*)h;
    *(uint4*)(xTh + o + 8) = *(uint4*)(h + 8);
    *(uint4*)(xTl + o) = *(uint4*)l;
    *(uint4*)(xTl + o + 8) = *(uint4*)(l + 8);
}

// ---------------------------------------------------------------------------
// 3-term fp16 hi/lo GEMM: C[m,n] = sum_k A[m,k]*B[n,k]
// 128x128 block tile, 4 waves, 16x16x32 f16 MFMA.
// EPI 0: Y epilogue (+bias, fp16 h/l; m<128 -> qkT transposed, else V)
// EPI 1: fp32 store (scores)
// ---------------------------------------------------------------------------
template <int EPI>
__global__ __launch_bounds__(256) void mfma3(
    const ushort_t* __restrict__ Ah, const ushort_t* __restrict__ Al, int aStride,
    const ushort_t* __restrict__ Bh, const ushort_t* __restrict__ Bl, int bStride,
    int kLen,
    const float* __restrict__ bq, const float* __restrict__ bk,
    const float* __restrict__ bv,
    ushort_t* __restrict__ qkTh, ushort_t* __restrict__ qkTl,
    ushort_t* __restrict__ Vh, ushort_t* __restrict__ Vl,
    float* __restrict__ outF) {
    __shared__ ushort_t sAh[128 * 32];
    __shared__ ushort_t sAl[128 * 32];
    __shared__ ushort_t sBh[128 * 32];
    __shared__ ushort_t sBl[128 * 32];

    const int tid = threadIdx.x, w = tid >> 6, lane = tid & 63;
    const int quad = lane >> 4, lr = lane & 15;
    const int m0 = blockIdx.y * 128, n0 = blockIdx.x * 128;

    const ushort_t* src;
    ushort_t* dst;
    int stride, rowBase;
    if (w == 0)      { src = Ah; dst = sAh; stride = aStride; rowBase = m0; }
    else if (w == 1) { src = Al; dst = sAl; stride = aStride; rowBase = m0; }
    else if (w == 2) { src = Bh; dst = sBh; stride = bStride; rowBase = n0; }
    else             { src = Bl; dst = sBl; stride = bStride; rowBase = n0; }
    const int cr = lane >> 2, kp = (lane & 3) << 3;
    const ushort_t* gk = src + (size_t)(rowBase + cr) * stride + kp;

    const int wm = (w & 1) * 64, wn = (w >> 1) * 64;

    float4v acc[4][4];
#pragma unroll
    for (int i = 0; i < 4; i++)
#pragma unroll
        for (int j = 0; j < 4; j++) acc[i][j] = (float4v){0.f, 0.f, 0.f, 0.f};

    for (int kk = 0; kk < kLen; kk += 32) {
#pragma unroll
        for (int c = 0; c < 8; c++)
            gl2lds16(gk + (size_t)(c * 16) * stride + kk, dst + c * 512);
        __syncthreads();

        short8 ah[4], al[4], bh[4], bl[4];
#pragma unroll
        for (int i = 0; i < 4; i++) {
            ah[i] = *(const short8*)&sAh[(wm + i * 16 + lr) * 32 + quad * 8];
            al[i] = *(const short8*)&sAl[(wm + i * 16 + lr) * 32 + quad * 8];
            bh[i] = *(const short8*)&sBh[(wn + i * 16 + lr) * 32 + quad * 8];
            bl[i] = *(const short8*)&sBl[(wn + i * 16 + lr) * 32 + quad * 8];
        }
#pragma unroll
        for (int i = 0; i < 4; i++)
#pragma unroll
            for (int j = 0; j < 4; j++) {
                acc[i][j] = __builtin_amdgcn_mfma_f32_16x16x32_f16(ah[i], bh[j], acc[i][j], 0, 0, 0);
                acc[i][j] = __builtin_amdgcn_mfma_f32_16x16x32_f16(ah[i], bl[j], acc[i][j], 0, 0, 0);
                acc[i][j] = __builtin_amdgcn_mfma_f32_16x16x32_f16(al[i], bh[j], acc[i][j], 0, 0, 0);
            }
        __syncthreads();
    }

    if (EPI == 0) {
#pragma unroll
        for (int i = 0; i < 4; i++)
#pragma unroll
            for (int j = 0; j < 4; j++)
#pragma unroll
                for (int r = 0; r < 4; r++) {
                    const int m = m0 + wm + i * 16 + quad * 4 + r;
                    const int n = n0 + wn + j * 16 + lr;
                    float bi = (m < C_Q) ? bq[m]
                              : (m < 2 * C_Q) ? bk[m - C_Q] : bv[m - 2 * C_Q];
                    float v = acc[i][j][r] + bi;
                    ushort_t h = f2h(v);
                    ushort_t lo = f2h(v - h2f(h));
                    if (m < 2 * C_Q) {
                        qkTh[(size_t)n * (2 * C_Q) + m] = h;
                        qkTl[(size_t)n * (2 * C_Q) + m] = lo;
                    } else {
                        Vh[(size_t)(m - 2 * C_Q) * HW_N + n] = h;
                        Vl[(size_t)(m - 2 * C_Q) * HW_N + n] = lo;
                    }
                }
    } else {
#pragma unroll
        for (int i = 0; i < 4; i++)
#pragma unroll
            for (int j = 0; j < 4; j++)
#pragma unroll
                for (int r = 0; r < 4; r++) {
                    const int m = m0 + wm + i * 16 + quad * 4 + r;
                    const int n = n0 + wn + j * 16 + lr;
                    outF[(size_t)m * HW_N + n] = acc[i][j][r];
                }
    }
}

// ---------------------------------------------------------------------------
// Row softmax in place over fp32 scores; writes SINGLE fp16 into the first
// half of each row (row i: ushort ofs i*8192, entries 0..4095).
// ---------------------------------------------------------------------------
__global__ __launch_bounds__(256) void softmax_rows_h(float* __restrict__ S) {
    __shared__ float red[256];
    const int t = threadIdx.x;
    float* p = S + (size_t)blockIdx.x * HW_N;
    const float4* p4 = (const float4*)p;

    float4 v[4];
    float m = -1e30f;
#pragma unroll
    for (int e = 0; e < 4; e++) {
        v[e] = p4[t + e * 256];
        m = fmaxf(m, fmaxf(fmaxf(v[e].x, v[e].y), fmaxf(v[e].z, v[e].w)));
    }
    red[t] = m;
    __syncthreads();
    for (int s = 128; s > 0; s >>= 1) {
        if (t < s) red[t] = fmaxf(red[t], red[t + s]);
        __syncthreads();
    }
    m = red[0];
    __syncthreads();

    float sum = 0.f;
#pragma unroll
    for (int e = 0; e < 4; e++) {
        v[e].x = __expf(v[e].x - m);
        v[e].y = __expf(v[e].y - m);
        v[e].z = __expf(v[e].z - m);
        v[e].w = __expf(v[e].w - m);
        sum += v[e].x + v[e].y + v[e].z + v[e].w;
    }
    red[t] = sum;
    __syncthreads();
    for (int s = 128; s > 0; s >>= 1) {
        if (t < s) red[t] += red[t + s];
        __syncthreads();
    }
    const float inv = 1.0f / red[0];

    ushort_t* ph = (ushort_t*)p;
#pragma unroll
    for (int e = 0; e < 4; e++) {
        ushort_t h4[4];
        h4[0] = f2h(v[e].x * inv);
        h4[1] = f2h(v[e].y * inv);
        h4[2] = f2h(v[e].z * inv);
        h4[3] = f2h(v[e].w * inv);
        *(uint2*)(ph + 4 * (t + e * 256)) = *(uint2*)h4;
    }
}

// ---------------------------------------------------------------------------
// feat 2-term GEMM: part[m,n] = sum_k (Vh+Vl)[m,k] * Ph[n,k]
// TM=128, TN=64. Attn rows at ushort stride 8192 (h in first half).
// ---------------------------------------------------------------------------
__global__ __launch_bounds__(256) void feat2(const ushort_t* __restrict__ Vh,
                                             const ushort_t* __restrict__ Vl,
                                             const ushort_t* __restrict__ attn,
                                             float* __restrict__ part,
                                             int kLen, size_t partStride) {
    __shared__ ushort_t sVh[128 * 32];
    __shared__ ushort_t sVl[128 * 32];
    __shared__ ushort_t sPh[64 * 32];

    const int tid = threadIdx.x, w = tid >> 6, lane = tid & 63;
    const int quad = lane >> 4, lr = lane & 15;
    const int m0 = blockIdx.y * 128, n0 = blockIdx.x * 64;
    const int k0 = blockIdx.z * kLen;

    const int cr = lane >> 2, kp = (lane & 3) << 3;

    const int wm = (w & 1) * 64, wn = (w >> 1) * 32;

    float4v acc[4][2];
#pragma unroll
    for (int i = 0; i < 4; i++)
#pragma unroll
        for (int j = 0; j < 2; j++) acc[i][j] = (float4v){0.f, 0.f, 0.f, 0.f};

    for (int kk = 0; kk < kLen; kk += 32) {
        // 20 chunks: 0-7 Vh, 8-15 Vl, 16-19 Ph; wave w stages [5w, 5w+5)
#pragma unroll
        for (int c = 0; c < 5; c++) {
            const int cg = w * 5 + c;
            const ushort_t* src;
            ushort_t* dst;
            if (cg < 8) {
                src = Vh + (size_t)(m0 + cg * 16 + cr) * HW_N;
                dst = sVh + cg * 512;
            } else if (cg < 16) {
                src = Vl + (size_t)(m0 + (cg - 8) * 16 + cr) * HW_N;
                dst = sVl + (cg - 8) * 512;
            } else {
                src = attn + (size_t)(n0 + (cg - 16) * 16 + cr) * (2 * HW_N);
                dst = sPh + (cg - 16) * 512;
            }
            gl2lds16(src + kp + k0 + kk, dst);
        }
        __syncthreads();

        short8 ah[4], al[4], bh[2];
#pragma unroll
        for (int i = 0; i < 4; i++) {
            ah[i] = *(const short8*)&sVh[(wm + i * 16 + lr) * 32 + quad * 8];
            al[i] = *(const short8*)&sVl[(wm + i * 16 + lr) * 32 + quad * 8];
        }
#pragma unroll
        for (int j = 0; j < 2; j++)
            bh[j] = *(const short8*)&sPh[(wn + j * 16 + lr) * 32 + quad * 8];
#pragma unroll
        for (int i = 0; i < 4; i++)
#pragma unroll
            for (int j = 0; j < 2; j++) {
                acc[i][j] = __builtin_amdgcn_mfma_f32_16x16x32_f16(ah[i], bh[j], acc[i][j], 0, 0, 0);
                acc[i][j] = __builtin_amdgcn_mfma_f32_16x16x32_f16(al[i], bh[j], acc[i][j], 0, 0, 0);
            }
        __syncthreads();
    }

    float* o = part + (size_t)blockIdx.z * partStride;
#pragma unroll
    for (int i = 0; i < 4; i++)
#pragma unroll
        for (int j = 0; j < 2; j++)
#pragma unroll
            for (int r = 0; r < 4; r++) {
                const int m = m0 + wm + i * 16 + quad * 4 + r;
                const int n = n0 + wn + j * 16 + lr;
                o[(size_t)m * HW_N + n] = acc[i][j][r];
            }
}

// out = alpha * sum_z part[z], float4-vectorized
__global__ __launch_bounds__(256) void reduce_alpha(const float4* __restrict__ part,
                                                    int kparts, size_t stride4,
                                                    const float* __restrict__ alpha,
                                                    float4* __restrict__ out) {
    const size_t i = (size_t)blockIdx.x * 256 + threadIdx.x;
    const float a = alpha[0];
    float4 s = part[i];
    for (int z = 1; z < kparts; z++) {
        float4 p = part[i + (size_t)z * stride4];
        s.x += p.x; s.y += p.y; s.z += p.z; s.w += p.w;
    }
    float4 o;
    o.x = a * s.x; o.y = a * s.y; o.z = a * s.z; o.w = a * s.w;
    out[i] = o;
}

// ---------------------------------------------------------------------------

extern "C" void kernel_launch(void* const* d_in, const int* in_sizes, int n_in,
                              void* d_out, int out_size, void* d_ws, size_t ws_size,
                              hipStream_t stream) {
    const float* x     = (const float*)d_in[0];
    const float* Wq    = (const float*)d_in[1];
    const float* bq    = (const float*)d_in[2];
    const float* Wk    = (const float*)d_in[3];
    const float* bk    = (const float*)d_in[4];
    const float* Wv    = (const float*)d_in[5];
    const float* bv    = (const float*)d_in[6];
    const float* alpha = (const float*)d_in[7];
    float* out = (float*)d_out;

    // ws layout:
    //   qkTh/qkTl : 4096 x 128 fp16 each            (2.1 MB)
    //   Vh/Vl     : 512 x 4096 fp16 each            (8.4 MB)
    //   scores    : 4096 x 4096 fp32                (67.1 MB) -> attn fp16 in place
    //     overlay (dead before scores written): xTh/xTl (8.4 MB), Wh/Wl (1.3 MB)
    //   part      : kparts x 512 x 4096 fp32
    ushort_t* qkTh = (ushort_t*)d_ws;
    ushort_t* qkTl = qkTh + (size_t)HW_N * 2 * C_Q;
    ushort_t* Vh   = qkTl + (size_t)HW_N * 2 * C_Q;
    ushort_t* Vl   = Vh + (size_t)C_IN * HW_N;
    float* scores  = (float*)(Vl + (size_t)C_IN * HW_N);
    float* part    = scores + (size_t)HW_N * HW_N;

    ushort_t* xTh = (ushort_t*)scores;
    ushort_t* xTl = xTh + (size_t)HW_N * C_IN;
    ushort_t* Wh  = xTl + (size_t)HW_N * C_IN;
    ushort_t* Wl  = Wh + (size_t)M_Y * C_IN;

    const size_t fixed_bytes = (size_t)HW_N * 2 * C_Q * 2 * 2
                             + (size_t)C_IN * HW_N * 2 * 2
                             + (size_t)HW_N * HW_N * 4;
    const size_t part_bytes = (size_t)C_IN * HW_N * 4;
    const int kparts = (ws_size >= fixed_bytes + 4 * part_bytes) ? 4 : 2;

    for (int b = 0; b < NB; b++) {
        const float* xb = x + (size_t)b * C_IN * HW_N;
        float* outb = out + (size_t)b * C_IN * HW_N;

        split_w<<<dim3(M_Y * C_IN / 4 / 256), dim3(256), 0, stream>>>(Wq, Wk, Wv, Wh, Wl);
        split_x<<<dim3(HW_N / 64, C_IN / 64), dim3(256), 0, stream>>>(xb, xTh, xTl);

        // Y = W*x + b -> qkT (transposed, m<128) and V (m>=128), fp16 h/l
        mfma3<0><<<dim3(HW_N / 128, M_Y / 128), dim3(256), 0, stream>>>(
            Wh, Wl, C_IN, xTh, xTl, C_IN, C_IN,
            bq, bk, bv, qkTh, qkTl, Vh, Vl, nullptr);

        // S[i,j] = sum_c q[c,i]k[c,j]
        mfma3<1><<<dim3(HW_N / 128, HW_N / 128), dim3(256), 0, stream>>>(
            qkTh, qkTl, 2 * C_Q, qkTh + C_Q, qkTl + C_Q, 2 * C_Q, C_Q,
            nullptr, nullptr, nullptr, nullptr, nullptr, nullptr, nullptr,
            scores);

        softmax_rows_h<<<dim3(HW_N), dim3(256), 0, stream>>>(scores);

        // feat partials: part[c,i] = sum_j (Vh+Vl)[c,j]*attnh[i,j]
        const ushort_t* attn = (const ushort_t*)scores;
        feat2<<<dim3(HW_N / 64, C_IN / 128, kparts), dim3(256), 0, stream>>>(
            Vh, Vl, attn, part, HW_N / kparts, (size_t)C_IN * HW_N);

        reduce_alpha<<<dim3((C_IN * HW_N / 4) / 256), dim3(256), 0, stream>>>(
            (const float4*)part, kparts, (size_t)C_IN * HW_N / 4, alpha,
            (float4*)outb);
    }
}

// Round 5
// 677.310 us; speedup vs baseline: 2.6780x; 1.0061x over previous
//
#include <hip/hip_runtime.h>
#include <hip/hip_fp16.h>

// Problem constants (fixed by setup_inputs)
#define HW_N 4096   // 64*64 spatial positions
#define C_IN 512    // channels
#define C_Q  64     // query/key channels
#define NB   4      // batch
#define M_Y  640    // Cq + Cq + C stacked output rows

typedef __attribute__((ext_vector_type(8))) short short8;
typedef __attribute__((ext_vector_type(4))) float float4v;
typedef unsigned short ushort_t;

__device__ __forceinline__ ushort_t f2h(float x) {
    return __half_as_ushort(__float2half(x));  // RNE
}
__device__ __forceinline__ float h2f(ushort_t h) {
    return __half2float(__ushort_as_half(h));
}
__device__ __forceinline__ void gl2lds16(const ushort_t* g, ushort_t* l) {
    __builtin_amdgcn_global_load_lds(
        (const __attribute__((address_space(1))) unsigned int*)g,
        (__attribute__((address_space(3))) unsigned int*)l, 16, 0, 0);
}
__device__ __forceinline__ void gl2lds16f(const float* g, float* l) {
    __builtin_amdgcn_global_load_lds(
        (const __attribute__((address_space(1))) unsigned int*)g,
        (__attribute__((address_space(3))) unsigned int*)l, 16, 0, 0);
}

// ---------------------------------------------------------------------------
// split stacked W = [Wq;Wk;Wv] (640x512 fp32) -> fp16 hi/lo
// ---------------------------------------------------------------------------
__global__ __launch_bounds__(256) void split_w(const float* __restrict__ Wq,
                                               const float* __restrict__ Wk,
                                               const float* __restrict__ Wv,
                                               ushort_t* __restrict__ Wh,
                                               ushort_t* __restrict__ Wl) {
    int idx = (blockIdx.x * 256 + threadIdx.x) * 4;
#pragma unroll
    for (int e = 0; e < 4; e++) {
        int i = idx + e;
        int m = i >> 9, k = i & 511;
        float v = (m < C_Q) ? Wq[m * C_IN + k]
                 : (m < 2 * C_Q) ? Wk[(m - C_Q) * C_IN + k]
                 : Wv[(size_t)(m - 2 * C_Q) * C_IN + k];
        ushort_t h = f2h(v);
        Wh[i] = h;
        Wl[i] = f2h(v - h2f(h));
    }
}

// ---------------------------------------------------------------------------
// transpose + split: x [512][4096] fp32 -> xT hi/lo [4096][512] fp16
// ---------------------------------------------------------------------------
__global__ __launch_bounds__(256) void split_x(const float* __restrict__ x,
                                               ushort_t* __restrict__ xTh,
                                               ushort_t* __restrict__ xTl) {
    __shared__ float tile[64][65];
    const int n0 = blockIdx.x * 64, k0 = blockIdx.y * 64;
    const int t = threadIdx.x;
#pragma unroll
    for (int it = 0; it < 4; it++) {
        int e = t + it * 256;
        int r = e >> 4, c4 = (e & 15) << 2;
        float4 v = *(const float4*)(x + (size_t)(k0 + r) * HW_N + n0 + c4);
        tile[r][c4 + 0] = v.x; tile[r][c4 + 1] = v.y;
        tile[r][c4 + 2] = v.z; tile[r][c4 + 3] = v.w;
    }
    __syncthreads();
    const int rr = t >> 2, kq = (t & 3) << 4;
    ushort_t h[16], l[16];
#pragma unroll
    for (int j = 0; j < 16; j++) {
        float v = tile[kq + j][rr];
        h[j] = f2h(v);
        l[j] = f2h(v - h2f(h[j]));
    }
    size_t o = (size_t)(n0 + rr) * C_IN + k0 + kq;
    *(uint4*)(xTh + o) = *(uint4*)h;
    *(uint4*)(xTh + o + 8) = *(uint4*)(h + 8);
    *(uint4*)(xTl + o) = *(uint4*)l;
    *(uint4*)(xTl + o + 8) = *(uint4*)(l + 8);
}

// ---------------------------------------------------------------------------
// 3-term fp16 hi/lo GEMM: C[m,n] = sum_k A[m,k]*B[n,k]
// 128x128 block tile, 4 waves, 16x16x32 f16 MFMA.
// EPI 0: Y epilogue (+bias, fp16 h/l; m<128 -> qkT transposed, else V)
// EPI 1: fp32 store (scores)
// ---------------------------------------------------------------------------
template <int EPI>
__global__ __launch_bounds__(256) void mfma3(
    const ushort_t* __restrict__ Ah, const ushort_t* __restrict__ Al, int aStride,
    const ushort_t* __restrict__ Bh, const ushort_t* __restrict__ Bl, int bStride,
    int kLen,
    const float* __restrict__ bq, const float* __restrict__ bk,
    const float* __restrict__ bv,
    ushort_t* __restrict__ qkTh, ushort_t* __restrict__ qkTl,
    ushort_t* __restrict__ Vh, ushort_t* __restrict__ Vl,
    float* __restrict__ outF) {
    __shared__ ushort_t sAh[128 * 32];
    __shared__ ushort_t sAl[128 * 32];
    __shared__ ushort_t sBh[128 * 32];
    __shared__ ushort_t sBl[128 * 32];

    const int tid = threadIdx.x, w = tid >> 6, lane = tid & 63;
    const int quad = lane >> 4, lr = lane & 15;
    const int m0 = blockIdx.y * 128, n0 = blockIdx.x * 128;

    const ushort_t* src;
    ushort_t* dst;
    int stride, rowBase;
    if (w == 0)      { src = Ah; dst = sAh; stride = aStride; rowBase = m0; }
    else if (w == 1) { src = Al; dst = sAl; stride = aStride; rowBase = m0; }
    else if (w == 2) { src = Bh; dst = sBh; stride = bStride; rowBase = n0; }
    else             { src = Bl; dst = sBl; stride = bStride; rowBase = n0; }
    const int cr = lane >> 2, kp = (lane & 3) << 3;
    const ushort_t* gk = src + (size_t)(rowBase + cr) * stride + kp;

    const int wm = (w & 1) * 64, wn = (w >> 1) * 64;

    float4v acc[4][4];
#pragma unroll
    for (int i = 0; i < 4; i++)
#pragma unroll
        for (int j = 0; j < 4; j++) acc[i][j] = (float4v){0.f, 0.f, 0.f, 0.f};

    for (int kk = 0; kk < kLen; kk += 32) {
#pragma unroll
        for (int c = 0; c < 8; c++)
            gl2lds16(gk + (size_t)(c * 16) * stride + kk, dst + c * 512);
        __syncthreads();

        short8 ah[4], al[4], bh[4], bl[4];
#pragma unroll
        for (int i = 0; i < 4; i++) {
            ah[i] = *(const short8*)&sAh[(wm + i * 16 + lr) * 32 + quad * 8];
            al[i] = *(const short8*)&sAl[(wm + i * 16 + lr) * 32 + quad * 8];
            bh[i] = *(const short8*)&sBh[(wn + i * 16 + lr) * 32 + quad * 8];
            bl[i] = *(const short8*)&sBl[(wn + i * 16 + lr) * 32 + quad * 8];
        }
#pragma unroll
        for (int i = 0; i < 4; i++)
#pragma unroll
            for (int j = 0; j < 4; j++) {
                acc[i][j] = __builtin_amdgcn_mfma_f32_16x16x32_f16(ah[i], bh[j], acc[i][j], 0, 0, 0);
                acc[i][j] = __builtin_amdgcn_mfma_f32_16x16x32_f16(ah[i], bl[j], acc[i][j], 0, 0, 0);
                acc[i][j] = __builtin_amdgcn_mfma_f32_16x16x32_f16(al[i], bh[j], acc[i][j], 0, 0, 0);
            }
        __syncthreads();
    }

    if (EPI == 0) {
#pragma unroll
        for (int i = 0; i < 4; i++)
#pragma unroll
            for (int j = 0; j < 4; j++)
#pragma unroll
                for (int r = 0; r < 4; r++) {
                    const int m = m0 + wm + i * 16 + quad * 4 + r;
                    const int n = n0 + wn + j * 16 + lr;
                    float bi = (m < C_Q) ? bq[m]
                              : (m < 2 * C_Q) ? bk[m - C_Q] : bv[m - 2 * C_Q];
                    float v = acc[i][j][r] + bi;
                    ushort_t h = f2h(v);
                    ushort_t lo = f2h(v - h2f(h));
                    if (m < 2 * C_Q) {
                        qkTh[(size_t)n * (2 * C_Q) + m] = h;
                        qkTl[(size_t)n * (2 * C_Q) + m] = lo;
                    } else {
                        Vh[(size_t)(m - 2 * C_Q) * HW_N + n] = h;
                        Vl[(size_t)(m - 2 * C_Q) * HW_N + n] = lo;
                    }
                }
    } else {
#pragma unroll
        for (int i = 0; i < 4; i++)
#pragma unroll
            for (int j = 0; j < 4; j++)
#pragma unroll
                for (int r = 0; r < 4; r++) {
                    const int m = m0 + wm + i * 16 + quad * 4 + r;
                    const int n = n0 + wn + j * 16 + lr;
                    outF[(size_t)m * HW_N + n] = acc[i][j][r];
                }
    }
}

// ---------------------------------------------------------------------------
// invD[i] = 1 / sum_j exp(S[i,j])  — no max subtraction (|S| << 88, fp32-safe)
// ---------------------------------------------------------------------------
__global__ __launch_bounds__(256) void rowsum_inv(const float* __restrict__ S,
                                                  float* __restrict__ invD) {
    __shared__ float red[256];
    const int t = threadIdx.x;
    const float4* p4 = (const float4*)(S + (size_t)blockIdx.x * HW_N);

    float sum = 0.f;
#pragma unroll
    for (int e = 0; e < 4; e++) {
        float4 v = p4[t + e * 256];
        sum += __expf(v.x) + __expf(v.y) + __expf(v.z) + __expf(v.w);
    }
    red[t] = sum;
    __syncthreads();
    for (int s = 128; s > 0; s >>= 1) {
        if (t < s) red[t] += red[t + s];
        __syncthreads();
    }
    if (t == 0) invD[blockIdx.x] = 1.0f / red[0];
}

// ---------------------------------------------------------------------------
// feat GEMM: part[m,n] = sum_k (Vh+Vl)[m,k] * P[n,k],
//   P[n,k] = f16( exp(S[n,k]) * invD[n] )   computed in-register.
// 128x128 tile, 4 waves 64x64. V tiles fp16 LDS (xor-swizzle, 4-way),
// S tile fp32 LDS (xor-swizzle, conflict-free).
// ---------------------------------------------------------------------------
__global__ __launch_bounds__(256) void feat3(const ushort_t* __restrict__ Vh,
                                             const ushort_t* __restrict__ Vl,
                                             const float* __restrict__ S,
                                             const float* __restrict__ invDg,
                                             float* __restrict__ part,
                                             int kLen, size_t partStride) {
    __shared__ ushort_t sVh[128 * 32];  // [row][unitP*8]; unitP = unitL ^ (row&3)
    __shared__ ushort_t sVl[128 * 32];
    __shared__ float    sS [128 * 32];  // [row][unitP*4]; unitP = unitL ^ (row&7)

    const int tid = threadIdx.x, w = tid >> 6, lane = tid & 63;
    const int quad = lane >> 4, lr = lane & 15;
    const int m0 = blockIdx.y * 128, n0 = blockIdx.x * 128;
    const int k0 = blockIdx.z * kLen;

    // staging lane geometry
    const int crv = lane >> 2, uv = lane & 3;   // V: 16 rows / chunk-instr
    const int crs = lane >> 3, us = lane & 7;   // S: 8 rows / chunk-instr
    const ushort_t* gVh = Vh + (size_t)(m0 + crv) * HW_N + ((uv ^ (crv & 3)) << 3) + k0;
    const ushort_t* gVl = Vl + (size_t)(m0 + crv) * HW_N + ((uv ^ (crv & 3)) << 3) + k0;
    const float*    gS  = S  + (size_t)(n0 + crs) * HW_N + ((us ^ (crs & 7)) << 2) + k0;

    const int wm = (w & 1) * 64, wn = (w >> 1) * 64;

    float invd[4];
#pragma unroll
    for (int j = 0; j < 4; j++) invd[j] = invDg[n0 + wn + j * 16 + lr];

    float4v acc[4][4];
#pragma unroll
    for (int i = 0; i < 4; i++)
#pragma unroll
        for (int j = 0; j < 4; j++) acc[i][j] = (float4v){0.f, 0.f, 0.f, 0.f};

    for (int kk = 0; kk < kLen; kk += 32) {
        if (w == 0) {
#pragma unroll
            for (int c = 0; c < 8; c++)
                gl2lds16(gVh + (size_t)(c * 16) * HW_N + kk, sVh + c * 512);
        } else if (w == 1) {
#pragma unroll
            for (int c = 0; c < 8; c++)
                gl2lds16(gVl + (size_t)(c * 16) * HW_N + kk, sVl + c * 512);
        } else if (w == 2) {
#pragma unroll
            for (int c = 0; c < 8; c++)
                gl2lds16f(gS + (size_t)(c * 8) * HW_N + kk, sS + c * 256);
        } else {
#pragma unroll
            for (int c = 8; c < 16; c++)
                gl2lds16f(gS + (size_t)(c * 8) * HW_N + kk, sS + c * 256);
        }
        __syncthreads();

        short8 ah[4], al[4], bh[4];
#pragma unroll
        for (int i = 0; i < 4; i++) {
            const int row = wm + i * 16 + lr;
            const int up = (quad ^ (lr & 3)) << 3;
            ah[i] = *(const short8*)&sVh[row * 32 + up];
            al[i] = *(const short8*)&sVl[row * 32 + up];
        }
#pragma unroll
        for (int j = 0; j < 4; j++) {
            const int row = wn + j * 16 + lr;
            float4 s0 = *(const float4*)&sS[row * 32 + (((quad * 2)     ^ (lr & 7)) << 2)];
            float4 s1 = *(const float4*)&sS[row * 32 + (((quad * 2 + 1) ^ (lr & 7)) << 2)];
            const float sc = invd[j];
            ushort_t hv[8];
            hv[0] = f2h(__expf(s0.x) * sc);
            hv[1] = f2h(__expf(s0.y) * sc);
            hv[2] = f2h(__expf(s0.z) * sc);
            hv[3] = f2h(__expf(s0.w) * sc);
            hv[4] = f2h(__expf(s1.x) * sc);
            hv[5] = f2h(__expf(s1.y) * sc);
            hv[6] = f2h(__expf(s1.z) * sc);
            hv[7] = f2h(__expf(s1.w) * sc);
            bh[j] = *(const short8*)hv;
        }
#pragma unroll
        for (int i = 0; i < 4; i++)
#pragma unroll
            for (int j = 0; j < 4; j++) {
                acc[i][j] = __builtin_amdgcn_mfma_f32_16x16x32_f16(ah[i], bh[j], acc[i][j], 0, 0, 0);
                acc[i][j] = __builtin_amdgcn_mfma_f32_16x16x32_f16(al[i], bh[j], acc[i][j], 0, 0, 0);
            }
        __syncthreads();
    }

    float* o = part + (size_t)blockIdx.z * partStride;
#pragma unroll
    for (int i = 0; i < 4; i++)
#pragma unroll
        for (int j = 0; j < 4; j++)
#pragma unroll
            for (int r = 0; r < 4; r++) {
                const int m = m0 + wm + i * 16 + quad * 4 + r;
                const int n = n0 + wn + j * 16 + lr;
                o[(size_t)m * HW_N + n] = acc[i][j][r];
            }
}

// out = alpha * sum_z part[z], float4-vectorized
__global__ __launch_bounds__(256) void reduce_alpha(const float4* __restrict__ part,
                                                    int kparts, size_t stride4,
                                                    const float* __restrict__ alpha,
                                                    float4* __restrict__ out) {
    const size_t i = (size_t)blockIdx.x * 256 + threadIdx.x;
    const float a = alpha[0];
    float4 s = part[i];
    for (int z = 1; z < kparts; z++) {
        float4 p = part[i + (size_t)z * stride4];
        s.x += p.x; s.y += p.y; s.z += p.z; s.w += p.w;
    }
    float4 o;
    o.x = a * s.x; o.y = a * s.y; o.z = a * s.z; o.w = a * s.w;
    out[i] = o;
}

// ---------------------------------------------------------------------------

extern "C" void kernel_launch(void* const* d_in, const int* in_sizes, int n_in,
                              void* d_out, int out_size, void* d_ws, size_t ws_size,
                              hipStream_t stream) {
    const float* x     = (const float*)d_in[0];
    const float* Wq    = (const float*)d_in[1];
    const float* bq    = (const float*)d_in[2];
    const float* Wk    = (const float*)d_in[3];
    const float* bk    = (const float*)d_in[4];
    const float* Wv    = (const float*)d_in[5];
    const float* bv    = (const float*)d_in[6];
    const float* alpha = (const float*)d_in[7];
    float* out = (float*)d_out;

    // ws layout:
    //   invD      : 4096 fp32                       (16 KB)
    //   qkTh/qkTl : 4096 x 128 fp16 each            (2.1 MB)
    //   Vh/Vl     : 512 x 4096 fp16 each            (8.4 MB)
    //   scores    : 4096 x 4096 fp32                (67.1 MB, stays fp32)
    //     overlay (dead before scores written): xTh/xTl (8.4 MB), Wh/Wl (1.3 MB)
    //   part      : kparts x 512 x 4096 fp32
    float* invD = (float*)d_ws;
    ushort_t* qkTh = (ushort_t*)(invD + HW_N);
    ushort_t* qkTl = qkTh + (size_t)HW_N * 2 * C_Q;
    ushort_t* Vh   = qkTl + (size_t)HW_N * 2 * C_Q;
    ushort_t* Vl   = Vh + (size_t)C_IN * HW_N;
    float* scores  = (float*)(Vl + (size_t)C_IN * HW_N);
    float* part    = scores + (size_t)HW_N * HW_N;

    ushort_t* xTh = (ushort_t*)scores;
    ushort_t* xTl = xTh + (size_t)HW_N * C_IN;
    ushort_t* Wh  = xTl + (size_t)HW_N * C_IN;
    ushort_t* Wl  = Wh + (size_t)M_Y * C_IN;

    const size_t fixed_bytes = (size_t)HW_N * 4
                             + (size_t)HW_N * 2 * C_Q * 2 * 2
                             + (size_t)C_IN * HW_N * 2 * 2
                             + (size_t)HW_N * HW_N * 4;
    const size_t part_bytes = (size_t)C_IN * HW_N * 4;
    const int kparts = (ws_size >= fixed_bytes + 4 * part_bytes) ? 4 : 2;

    for (int b = 0; b < NB; b++) {
        const float* xb = x + (size_t)b * C_IN * HW_N;
        float* outb = out + (size_t)b * C_IN * HW_N;

        split_w<<<dim3(M_Y * C_IN / 4 / 256), dim3(256), 0, stream>>>(Wq, Wk, Wv, Wh, Wl);
        split_x<<<dim3(HW_N / 64, C_IN / 64), dim3(256), 0, stream>>>(xb, xTh, xTl);

        // Y = W*x + b -> qkT (transposed, m<128) and V (m>=128), fp16 h/l
        mfma3<0><<<dim3(HW_N / 128, M_Y / 128), dim3(256), 0, stream>>>(
            Wh, Wl, C_IN, xTh, xTl, C_IN, C_IN,
            bq, bk, bv, qkTh, qkTl, Vh, Vl, nullptr);

        // S[i,j] = sum_c q[c,i]k[c,j]  (fp32, stays resident)
        mfma3<1><<<dim3(HW_N / 128, HW_N / 128), dim3(256), 0, stream>>>(
            qkTh, qkTl, 2 * C_Q, qkTh + C_Q, qkTl + C_Q, 2 * C_Q, C_Q,
            nullptr, nullptr, nullptr, nullptr, nullptr, nullptr, nullptr,
            scores);

        rowsum_inv<<<dim3(HW_N), dim3(256), 0, stream>>>(scores, invD);

        // feat partials: part[c,i] = sum_j (Vh+Vl)[c,j] * f16(exp(S[i,j])*invD[i])
        feat3<<<dim3(HW_N / 128, C_IN / 128, kparts), dim3(256), 0, stream>>>(
            Vh, Vl, scores, invD, part, HW_N / kparts, (size_t)C_IN * HW_N);

        reduce_alpha<<<dim3((C_IN * HW_N / 4) / 256), dim3(256), 0, stream>>>(
            (const float4*)part, kparts, (size_t)C_IN * HW_N / 4, alpha,
            (float4*)outb);
    }
}